// Round 1
// baseline (330.656 us; speedup 1.0000x reference)
//
#include <hip/hip_runtime.h>

// PointSample: bilinear grid_sample, align_corners=False, border clamp.
// features: [B=8, H=256, W=256, C=128] fp32 channels-last
// grid:     [B=8, P=8192, 2] fp32 (x, y) in [0, 1]
// out:      [B, P, C] fp32
//
// Mapping: one thread per (point, channel-quad). 32 consecutive lanes handle
// one point's 128 channels as float4 -> each corner gather is a coalesced
// 512 B contiguous read (rows are 512 B aligned since C*4 = 512).

constexpr int B = 8, H = 256, W = 256, C = 128, P = 8192;
constexpr int C4 = C / 4;           // 32 float4 chunks per point
constexpr int LOG2_C4 = 5;
constexpr int LOG2_P  = 13;

__global__ __launch_bounds__(256) void pointsample_kernel(
    const float4* __restrict__ feat,   // [B*H*W*C4] float4
    const float2* __restrict__ grid,   // [B*P] (x,y)
    float4* __restrict__ out)          // [B*P*C4]
{
    const int t  = blockIdx.x * blockDim.x + threadIdx.x;
    const int c4 = t & (C4 - 1);        // channel-quad index 0..31
    const int pg = t >> LOG2_C4;        // global point index 0..B*P-1
    const int b  = pg >> LOG2_P;        // batch index

    // --- point coords & bilinear weights (mirror reference expression order)
    const float2 g = grid[pg];
    const float x = g.x * 2.0f - 1.0f;
    const float y = g.y * 2.0f - 1.0f;
    const float ix = ((x + 1.0f) * (float)W - 1.0f) * 0.5f;
    const float iy = ((y + 1.0f) * (float)H - 1.0f) * 0.5f;
    const float x0f = floorf(ix);
    const float y0f = floorf(iy);
    const float wx = ix - x0f;
    const float wy = iy - y0f;
    const int xi = (int)x0f;
    const int yi = (int)y0f;
    const int x0 = min(max(xi,     0), W - 1);
    const int x1 = min(max(xi + 1, 0), W - 1);
    const int y0 = min(max(yi,     0), H - 1);
    const int y1 = min(max(yi + 1, 0), H - 1);

    // --- 4 corner gathers (each 512 B contiguous across the 32-lane group)
    const float4* fb = feat + (size_t)b * (size_t)(H * W) * C4;
    const size_t r0 = (size_t)(y0 * W) * C4;
    const size_t r1 = (size_t)(y1 * W) * C4;
    const float4 c00 = fb[r0 + (size_t)x0 * C4 + c4];
    const float4 c01 = fb[r0 + (size_t)x1 * C4 + c4];
    const float4 c10 = fb[r1 + (size_t)x0 * C4 + c4];
    const float4 c11 = fb[r1 + (size_t)x1 * C4 + c4];

    const float w00 = (1.0f - wy) * (1.0f - wx);
    const float w01 = (1.0f - wy) * wx;
    const float w10 = wy * (1.0f - wx);
    const float w11 = wy * wx;

    float4 o;
    o.x = c00.x * w00 + c01.x * w01 + c10.x * w10 + c11.x * w11;
    o.y = c00.y * w00 + c01.y * w01 + c10.y * w10 + c11.y * w11;
    o.z = c00.z * w00 + c01.z * w01 + c10.z * w10 + c11.z * w11;
    o.w = c00.w * w00 + c01.w * w01 + c10.w * w10 + c11.w * w11;

    out[(size_t)pg * C4 + c4] = o;
}

extern "C" void kernel_launch(void* const* d_in, const int* in_sizes, int n_in,
                              void* d_out, int out_size, void* d_ws, size_t ws_size,
                              hipStream_t stream) {
    const float4* feat = (const float4*)d_in[0];
    const float2* grd  = (const float2*)d_in[1];
    float4*       out  = (float4*)d_out;

    constexpr int total_threads = B * P * C4;   // 2,097,152
    constexpr int block = 256;
    constexpr int nblocks = total_threads / block; // 8192, exact

    pointsample_kernel<<<nblocks, block, 0, stream>>>(feat, grd, out);
}